// Round 9
// baseline (1538.062 us; speedup 1.0000x reference)
//
#include <hip/hip_runtime.h>
#include <hip/hip_bf16.h>

// Problem constants (BoW mini-GPT forward): B=4 T=2048 V=50257 C=512 H=2048
#define B_    4
#define T_    2048
#define V_    50257
#define C_    512
#define H_    2048
#define BT_   8192
#define VPAD_ 50432   // 197*256
#define MB_   ((size_t)1 << 20)

typedef unsigned short u16;
typedef __attribute__((ext_vector_type(8))) short bf16x8;
typedef __attribute__((ext_vector_type(4))) float f32x4;
typedef __attribute__((ext_vector_type(4), aligned(16))) float f32x4a;
typedef const __attribute__((address_space(1))) unsigned gu32;
typedef __attribute__((address_space(3))) unsigned su32;

__device__ __forceinline__ u16 f2bf(float f) {
    unsigned u = __builtin_bit_cast(unsigned, f);
    u = u + 0x7fffu + ((u >> 16) & 1u);   // round-to-nearest-even
    return (u16)(u >> 16);
}

// ---------------- embedding + causal BoW (3 small kernels) --------------------------
__global__ void emb_kernel(const int* __restrict__ x, const float* __restrict__ wte,
                           const float* __restrict__ wpe, float* __restrict__ emb,
                           float* __restrict__ S)
{
    int bid = blockIdx.x;
    int cg  = bid & 1;
    int ch  = (bid >> 1) & 15;
    int b   = bid >> 5;
    int c   = cg * 256 + threadIdx.x;
    __shared__ int toks[128];
    if (threadIdx.x < 128) toks[threadIdx.x] = x[b * T_ + ch * 128 + threadIdx.x];
    __syncthreads();
    float sum = 0.f;
    #pragma unroll 4
    for (int tt = 0; tt < 128; ++tt) {
        int t = ch * 128 + tt;
        float e = wte[(size_t)toks[tt] * C_ + c] + wpe[(size_t)t * C_ + c];
        emb[(size_t)(b * T_ + t) * C_ + c] = e;
        sum += e;
    }
    S[(b * 16 + ch) * C_ + c] = sum;
}

__global__ void scan_kernel(const float* __restrict__ S, float* __restrict__ P)
{
    int idx = blockIdx.x * 256 + threadIdx.x;   // 0..2047
    int b = idx >> 9, c = idx & 511;
    float run = 0.f;
    #pragma unroll
    for (int ch = 0; ch < 16; ++ch) {
        P[(b * 16 + ch) * C_ + c] = run;
        run += S[(b * 16 + ch) * C_ + c];
    }
}

__global__ void bow_kernel(const float* __restrict__ emb, const float* __restrict__ P,
                           float* __restrict__ h1f, u16* __restrict__ h1b)
{
    int bid = blockIdx.x;
    int cg  = bid & 1;
    int ch  = (bid >> 1) & 15;
    int b   = bid >> 5;
    int c   = cg * 256 + threadIdx.x;
    float run = P[(b * 16 + ch) * C_ + c];
    #pragma unroll 4
    for (int tt = 0; tt < 128; ++tt) {
        int t = ch * 128 + tt;
        size_t idx = (size_t)(b * T_ + t) * C_ + c;
        float e = emb[idx];
        run += e;
        float h = e + run / (float)(t + 1);
        h1f[idx] = h;
        h1b[idx] = f2bf(h);
    }
}

// transpose + fp32->bf16 convert: Wt[v][k] = W[k][colStart+v], zero-pad v>=N.
__global__ void tconv_kernel(const float* __restrict__ W, u16* __restrict__ Wt,
                             int K, int N, int colStart, int nCols)
{
    __shared__ float tile[32][33];
    int v0 = blockIdx.x * 32, k0 = blockIdx.y * 32;
    int tx = threadIdx.x, ty = threadIdx.y;
    #pragma unroll
    for (int r = 0; r < 4; ++r) {
        int k = k0 + ty + r * 8;
        int v = colStart + v0 + tx;
        tile[ty + r * 8][tx] = (v < N) ? W[(size_t)k * N + v] : 0.f;
    }
    __syncthreads();
    #pragma unroll
    for (int r = 0; r < 4; ++r) {
        int vl = ty + r * 8;
        Wt[(size_t)(v0 + vl) * K + k0 + tx] = f2bf(tile[tx][vl]);
    }
}

// ---------------- MLP bf16 MFMA GEMM (128x128x64, proven path) ----------------------
template <int EPI>
__global__ __launch_bounds__(256, 3)
void gemm_kernel(const u16* __restrict__ A, const u16* __restrict__ Bt,
                 int M, int N, int K,
                 const float* __restrict__ bias, const float* __restrict__ resid,
                 u16* __restrict__ outB, int ldOut)
{
    __shared__ char smem[32768];
    const int tid  = threadIdx.x;
    const int wid  = tid >> 6;
    const int lane = tid & 63;
    const int wm   = wid >> 1, wn = wid & 1;
    const int lr   = lane & 15;
    const int hi   = lane >> 4;

    const int NBX = N >> 7;
    const int NBY = M >> 7;
    const int nwg = NBX * NBY;
    const int per = nwg >> 3;
    const int wg  = (blockIdx.x & 7) * per + (blockIdx.x >> 3);
    const int grpSz  = NBY << 3;
    const int colgrp = wg / grpSz;
    const int baseBx = colgrp << 3;
    int wcols = NBX - baseBx; if (wcols > 8) wcols = 8;
    const int idx = wg - colgrp * grpSz;
    const int by  = idx / wcols;
    const int bx  = baseBx + idx % wcols;

    const int rowA0 = by * 128;
    const int colB0 = bx * 128;
    const int KT    = K / 64;

    auto stage = [&](int kt) {
        #pragma unroll
        for (int i = 0; i < 4; ++i) {
            int c    = i * 256 + tid;
            int row  = c >> 3;
            int slot = (c & 7) ^ (row & 7);
            const u16* ga = A  + (size_t)(rowA0 + row) * K + kt * 64 + slot * 8;
            const u16* gb = Bt + (size_t)(colB0 + row) * K + kt * 64 + slot * 8;
            int ldsOff = i * 4096 + wid * 1024;
            __builtin_amdgcn_global_load_lds((gu32*)ga, (su32*)(smem + ldsOff),         16, 0, 0);
            __builtin_amdgcn_global_load_lds((gu32*)gb, (su32*)(smem + 16384 + ldsOff), 16, 0, 0);
        }
    };

    f32x4 acc[4][4];
    #pragma unroll
    for (int m = 0; m < 4; ++m)
        #pragma unroll
        for (int n = 0; n < 4; ++n) acc[m][n] = f32x4{0.f, 0.f, 0.f, 0.f};

    for (int kt = 0; kt < KT; ++kt) {
        stage(kt);
        __syncthreads();
        #pragma unroll
        for (int ks = 0; ks < 2; ++ks) {
            bf16x8 af[4], bfr[4];
            #pragma unroll
            for (int m = 0; m < 4; ++m) {
                int row = wm * 64 + m * 16 + lr;
                int kbyte = (ks * 64 + hi * 16) ^ ((row & 7) << 4);
                af[m] = *(const bf16x8*)(smem + row * 128 + kbyte);
            }
            #pragma unroll
            for (int n = 0; n < 4; ++n) {
                int row = wn * 64 + n * 16 + lr;
                int kbyte = (ks * 64 + hi * 16) ^ ((row & 7) << 4);
                bfr[n] = *(const bf16x8*)(smem + 16384 + row * 128 + kbyte);
            }
            #pragma unroll
            for (int m = 0; m < 4; ++m)
                #pragma unroll
                for (int n = 0; n < 4; ++n)
                    acc[m][n] = __builtin_amdgcn_mfma_f32_16x16x32_bf16(af[m], bfr[n], acc[m][n], 0, 0, 0);
        }
        __syncthreads();
    }

    #pragma unroll
    for (int m = 0; m < 4; ++m) {
        #pragma unroll
        for (int n = 0; n < 4; ++n) {
            int gcol = colB0 + wn * 64 + n * 16 + lr;
            #pragma unroll
            for (int r = 0; r < 4; ++r) {
                int grow = rowA0 + wm * 64 + m * 16 + hi * 4 + r;
                float v = acc[m][n][r];
                if constexpr (EPI == 0) {
                    v = tanhf(v + bias[gcol]);
                } else {
                    v = v + bias[gcol] + resid[(size_t)grow * ldOut + gcol];
                }
                outB[(size_t)grow * ldOut + gcol] = f2bf(v);
            }
        }
    }
}

// ---------------- head GEMM: 128x256xK512, BK=32, A-direct-from-global --------------
// B-only LDS (3 bufs x 16KB = 48KB), 8 waves, 2 blocks/CU. A-fragments load straight
// global->VGPR (4 hi-lanes merge per 64B line; 4 wn-waves share lines via L1; blocks
// ordered bx-fastest so co-resident blocks share one 128KB A panel in L2, and B panels
// stream once to L3 which holds all ~49MB). LDS traffic per block-tile drops 88->48KB.
// Ledger: steady vmcnt(2); stage B(kt+2) at top, af(kt+1) issued after MFMAs.

#define ENDP { asm volatile("s_waitcnt lgkmcnt(0)" ::: "memory");                     \
               __builtin_amdgcn_sched_barrier(0);                                     \
               __builtin_amdgcn_s_barrier();                                          \
               __builtin_amdgcn_sched_barrier(0); }

#define WAITV(N) { asm volatile("s_waitcnt vmcnt(" #N ")" ::: "memory");              \
                   __builtin_amdgcn_sched_barrier(0);                                 \
                   __builtin_amdgcn_s_barrier();                                      \
                   __builtin_amdgcn_sched_barrier(0); }

__global__ __launch_bounds__(512, 2)
void head_kernel(const u16* __restrict__ A, const u16* __restrict__ Bt,
                 const float* __restrict__ bias, float* __restrict__ outF,
                 int colStart, int nbx)
{
    __shared__ char smem[49152];            // 3 x B buf 16KB; epilogue reuses as ebuf
    const int tid  = threadIdx.x;
    const int wid  = tid >> 6;
    const int lane = tid & 63;
    const int wm   = wid >> 2, wn = wid & 3;
    const int lr   = lane & 15;
    const int hi   = lane >> 4;

    // block mapping: bijective XCD chunks, bx-fastest (A-panel L2-shared per XCD)
    const int nwg = nbx * 64;
    const int per = nwg >> 3;               // nwg % 8 == 0
    const int wg  = (blockIdx.x & 7) * per + (blockIdx.x >> 3);
    const int by  = wg / nbx;
    const int bx  = wg - by * nbx;
    const int rowA0 = by * 128;
    const int colB0 = bx * 256;

    auto stageB = [&](int kt, int buf) {
        char* Bb = smem + buf * 16384;
        #pragma unroll
        for (int i = 0; i < 2; ++i) {
            int u = i * 512 + tid;
            int row = u >> 2, sc = u & 3, gs = sc ^ ((row >> 1) & 3);
            const u16* gb = Bt + (size_t)(colB0 + row) * C_ + kt * 32 + gs * 8;
            __builtin_amdgcn_global_load_lds((gu32*)gb, (su32*)(Bb + i * 8192 + wid * 1024), 16, 0, 0);
        }
    };

    // A-fragment lane base: row = rowA0 + wm*64 + m*16 + lr, k-slot = hi*8
    const u16* aBase = A + (size_t)(rowA0 + wm * 64 + lr) * C_ + hi * 8;
    bf16x8 af[4];
    auto loadA = [&](int kt) {
        #pragma unroll
        for (int m = 0; m < 4; ++m)
            af[m] = *(const bf16x8*)(aBase + (size_t)(m * 16) * C_ + kt * 32);
    };

    f32x4 acc[4][4];
    #pragma unroll
    for (int m = 0; m < 4; ++m)
        #pragma unroll
        for (int n = 0; n < 4; ++n) acc[m][n] = f32x4{0.f, 0.f, 0.f, 0.f};

    auto computeT = [&](int buf) {
        const char* Bb = smem + buf * 16384;
        bf16x8 bfr[4];
        #pragma unroll
        for (int n = 0; n < 4; ++n) {
            int r = wn * 64 + n * 16 + lr;
            bfr[n] = *(const bf16x8*)(Bb + (r * 4 + (hi ^ ((r >> 1) & 3))) * 16);
        }
        #pragma unroll
        for (int m = 0; m < 4; ++m)
            #pragma unroll
            for (int n = 0; n < 4; ++n)
                acc[m][n] = __builtin_amdgcn_mfma_f32_16x16x32_bf16(af[m], bfr[n], acc[m][n], 0, 0, 0);
    };

    // prologue: B tiles 0,1 staged; A frags for tile 0 in regs
    stageB(0, 0);
    stageB(1, 1);
    loadA(0);
    // main loop: 16 K-tiles of 32; steady vmcnt(2)
    for (int kt = 0; kt < 14; ++kt) {
        stageB(kt + 2, (kt + 2) % 3);
        WAITV(2)                            // drains stage(kt) + af(kt); 2 stay in flight
        computeT(kt % 3);
        loadA(kt + 1);                      // issued under/after MFMAs, lands by next wait
        ENDP
    }
    WAITV(0)
    computeT(14 % 3);
    loadA(15);
    ENDP
    WAITV(0)
    computeT(15 % 3);

    // ---- epilogue: 4 passes of 32 rows x 256 cols, LDS-staged, 16B-aligned stores --
    float* ebuf = (float*)smem;             // 32 x 264 floats = 33.8KB
    float biasr[4];
    #pragma unroll
    for (int nf = 0; nf < 4; ++nf) {
        int vc = colStart + colB0 + wn * 64 + nf * 16 + lr;
        biasr[nf] = (vc < V_) ? bias[vc] : 0.f;
    }
    const int er2 = tid >> 4;               // 0..31: output row owner
    const int kk  = tid & 15;
    #pragma unroll
    for (int mf = 0; mf < 4; ++mf) {
        __builtin_amdgcn_s_barrier();
        #pragma unroll
        for (int nf = 0; nf < 4; ++nf) {
            int ec = wn * 64 + nf * 16 + lr;
            int er = wm * 16 + hi * 4;
            #pragma unroll
            for (int r = 0; r < 4; ++r)
                ebuf[(er + r) * 264 + ec] = acc[mf][nf][r] + biasr[nf];
        }
        asm volatile("s_waitcnt lgkmcnt(0)" ::: "memory");
        __builtin_amdgcn_s_barrier();
        long grow = rowA0 + (er2 >> 4) * 64 + mf * 16 + (er2 & 15);
        long S    = grow * V_ + colStart + colB0;   // f32 flat index of col 0
        long a0   = (S + 3) & ~3L;                  // 16B-aligned start
        int  sh   = (int)(a0 - S);                  // 0..3
        const float* rowp = ebuf + er2 * 264;
        if (kk == 0) {
            for (int e = 0; e < sh; ++e) {          // head elems (cached: L2 merge)
                int vc = colStart + colB0 + e;
                if (vc < V_) outF[S + e] = rowp[e];
            }
        }
        #pragma unroll
        for (int j = 0; j < 4; ++j) {
            int  cb = sh + (kk + j * 16) * 4;       // block-local col of chunk
            long g  = a0 + (long)(kk + j * 16) * 4;
            int  vc = colStart + colB0 + cb;        // vocab col of first elem
            if (cb + 3 <= 255 && vc + 3 < V_) {
                f32x4a t = { rowp[cb], rowp[cb + 1], rowp[cb + 2], rowp[cb + 3] };
                __builtin_nontemporal_store(t, (f32x4a*)(outF + g));
            } else {
                #pragma unroll
                for (int e = 0; e < 4; ++e)
                    if (cb + e <= 255 && vc + e < V_)
                        outF[g + e] = rowp[cb + e];  // cached boundary stores
            }
        }
    }
}

// ------------------------------------------------------------------------------------
extern "C" void kernel_launch(void* const* d_in, const int* in_sizes, int n_in,
                              void* d_out, int out_size, void* d_ws, size_t ws_size,
                              hipStream_t stream)
{
    const int*   x      = (const int*)  d_in[0];
    const float* wte    = (const float*)d_in[1];
    const float* wpe    = (const float*)d_in[2];
    const float* w_fc   = (const float*)d_in[3];
    const float* b_fc   = (const float*)d_in[4];
    const float* w_proj = (const float*)d_in[5];
    const float* b_proj = (const float*)d_in[6];
    const float* w_head = (const float*)d_in[7];
    const float* b_head = (const float*)d_in[8];
    float* out = (float*)d_out;

    // Scratch inside d_out (dead before the head GEMM overwrites d_out)
    char*  ob   = (char*)d_out;
    float* emb  = (float*)(ob);                    // 16 MB
    float* h1f  = (float*)(ob + 16 * MB_);         // 16 MB
    u16*   h1b  = (u16*)  (ob + 32 * MB_);         //  8 MB
    u16*   actb = (u16*)  (ob + 40 * MB_);         // 32 MB
    u16*   wfct = (u16*)  (ob + 72 * MB_);         //  2 MB
    u16*   wprt = (u16*)  (ob + 74 * MB_);         //  2 MB
    float* S    = (float*)(ob + 76 * MB_);         // 128 KB
    float* P    = (float*)(ob + 76 * MB_ + 128 * 1024);

    // ws: only what must survive while the head GEMM writes d_out
    u16* h2b = (u16*)d_ws;                         // 8 MB
    u16* wht = (u16*)((char*)d_ws + 8 * MB_);      // head weight chunk (bf16, transposed)

    long availCols = 0;
    if (ws_size > 8 * MB_ + 512 * 1024)
        availCols = (long)((ws_size - 8 * MB_) / (C_ * 2));
    int chunk = (int)(availCols & ~255L);
    if (chunk < 256)   chunk = 256;
    if (chunk > VPAD_) chunk = VPAD_;

    // weights -> bf16 transposed (N-major, K-contiguous)
    tconv_kernel<<<dim3(H_ / 32, C_ / 32), dim3(32, 8), 0, stream>>>(w_fc,   wfct, C_, H_, 0, H_);
    tconv_kernel<<<dim3(C_ / 32, H_ / 32), dim3(32, 8), 0, stream>>>(w_proj, wprt, H_, C_, 0, C_);

    // embedding + causal BoW
    emb_kernel <<<128, 256, 0, stream>>>(x, wte, wpe, emb, S);
    scan_kernel<<<8,   256, 0, stream>>>(S, P);
    bow_kernel <<<128, 256, 0, stream>>>(emb, P, h1f, h1b);

    // MLP
    gemm_kernel<0><<<(H_ / 128) * (BT_ / 128), 256, 0, stream>>>(
        h1b, wfct, BT_, H_, C_, b_fc, nullptr, actb, H_);
    gemm_kernel<1><<<(C_ / 128) * (BT_ / 128), 256, 0, stream>>>(
        actb, wprt, BT_, C_, H_, b_proj, h1f, h2b, C_);

    // head: V processed in ws-sized column chunks
    for (int cs = 0; cs < VPAD_; cs += chunk) {
        int nc = VPAD_ - cs < chunk ? VPAD_ - cs : chunk;
        tconv_kernel<<<dim3(nc / 32, C_ / 32), dim3(32, 8), 0, stream>>>(
            w_head, wht, C_, V_, cs, nc);
        head_kernel<<<(nc / 256) * 64, 512, 0, stream>>>(
            h2b, wht, b_head, out, cs, nc / 256);
    }
}

// Round 10
// 880.489 us; speedup vs baseline: 1.7468x; 1.7468x over previous
//
#include <hip/hip_runtime.h>
#include <hip/hip_bf16.h>

// Problem constants (BoW mini-GPT forward): B=4 T=2048 V=50257 C=512 H=2048
#define B_    4
#define T_    2048
#define V_    50257
#define C_    512
#define H_    2048
#define BT_   8192
#define VPAD_ 50432   // 197*256
#define MB_   ((size_t)1 << 20)

typedef unsigned short u16;
typedef __attribute__((ext_vector_type(8))) short bf16x8;
typedef __attribute__((ext_vector_type(4))) float f32x4;
typedef __attribute__((ext_vector_type(4), aligned(16))) float f32x4a;
typedef const __attribute__((address_space(1))) unsigned gu32;
typedef __attribute__((address_space(3))) unsigned su32;

__device__ __forceinline__ u16 f2bf(float f) {
    unsigned u = __builtin_bit_cast(unsigned, f);
    u = u + 0x7fffu + ((u >> 16) & 1u);   // round-to-nearest-even
    return (u16)(u >> 16);
}

// ---------------- embedding + causal BoW (3 small kernels) --------------------------
__global__ void emb_kernel(const int* __restrict__ x, const float* __restrict__ wte,
                           const float* __restrict__ wpe, float* __restrict__ emb,
                           float* __restrict__ S)
{
    int bid = blockIdx.x;
    int cg  = bid & 1;
    int ch  = (bid >> 1) & 15;
    int b   = bid >> 5;
    int c   = cg * 256 + threadIdx.x;
    __shared__ int toks[128];
    if (threadIdx.x < 128) toks[threadIdx.x] = x[b * T_ + ch * 128 + threadIdx.x];
    __syncthreads();
    float sum = 0.f;
    #pragma unroll 4
    for (int tt = 0; tt < 128; ++tt) {
        int t = ch * 128 + tt;
        float e = wte[(size_t)toks[tt] * C_ + c] + wpe[(size_t)t * C_ + c];
        emb[(size_t)(b * T_ + t) * C_ + c] = e;
        sum += e;
    }
    S[(b * 16 + ch) * C_ + c] = sum;
}

__global__ void scan_kernel(const float* __restrict__ S, float* __restrict__ P)
{
    int idx = blockIdx.x * 256 + threadIdx.x;   // 0..2047
    int b = idx >> 9, c = idx & 511;
    float run = 0.f;
    #pragma unroll
    for (int ch = 0; ch < 16; ++ch) {
        P[(b * 16 + ch) * C_ + c] = run;
        run += S[(b * 16 + ch) * C_ + c];
    }
}

__global__ void bow_kernel(const float* __restrict__ emb, const float* __restrict__ P,
                           float* __restrict__ h1f, u16* __restrict__ h1b)
{
    int bid = blockIdx.x;
    int cg  = bid & 1;
    int ch  = (bid >> 1) & 15;
    int b   = bid >> 5;
    int c   = cg * 256 + threadIdx.x;
    float run = P[(b * 16 + ch) * C_ + c];
    #pragma unroll 4
    for (int tt = 0; tt < 128; ++tt) {
        int t = ch * 128 + tt;
        size_t idx = (size_t)(b * T_ + t) * C_ + c;
        float e = emb[idx];
        run += e;
        float h = e + run / (float)(t + 1);
        h1f[idx] = h;
        h1b[idx] = f2bf(h);
    }
}

// transpose + fp32->bf16 convert: Wt[v][k] = W[k][colStart+v], zero-pad v>=N.
__global__ void tconv_kernel(const float* __restrict__ W, u16* __restrict__ Wt,
                             int K, int N, int colStart, int nCols)
{
    __shared__ float tile[32][33];
    int v0 = blockIdx.x * 32, k0 = blockIdx.y * 32;
    int tx = threadIdx.x, ty = threadIdx.y;
    #pragma unroll
    for (int r = 0; r < 4; ++r) {
        int k = k0 + ty + r * 8;
        int v = colStart + v0 + tx;
        tile[ty + r * 8][tx] = (v < N) ? W[(size_t)k * N + v] : 0.f;
    }
    __syncthreads();
    #pragma unroll
    for (int r = 0; r < 4; ++r) {
        int vl = ty + r * 8;
        Wt[(size_t)(v0 + vl) * K + k0 + tx] = f2bf(tile[tx][vl]);
    }
}

// ---------------- MLP bf16 MFMA GEMM (128x128x64, proven path) ----------------------
template <int EPI>
__global__ __launch_bounds__(256, 3)
void gemm_kernel(const u16* __restrict__ A, const u16* __restrict__ Bt,
                 int M, int N, int K,
                 const float* __restrict__ bias, const float* __restrict__ resid,
                 u16* __restrict__ outB, int ldOut)
{
    __shared__ char smem[32768];
    const int tid  = threadIdx.x;
    const int wid  = tid >> 6;
    const int lane = tid & 63;
    const int wm   = wid >> 1, wn = wid & 1;
    const int lr   = lane & 15;
    const int hi   = lane >> 4;

    const int NBX = N >> 7;
    const int NBY = M >> 7;
    const int nwg = NBX * NBY;
    const int per = nwg >> 3;
    const int wg  = (blockIdx.x & 7) * per + (blockIdx.x >> 3);
    const int grpSz  = NBY << 3;
    const int colgrp = wg / grpSz;
    const int baseBx = colgrp << 3;
    int wcols = NBX - baseBx; if (wcols > 8) wcols = 8;
    const int idx = wg - colgrp * grpSz;
    const int by  = idx / wcols;
    const int bx  = baseBx + idx % wcols;

    const int rowA0 = by * 128;
    const int colB0 = bx * 128;
    const int KT    = K / 64;

    auto stage = [&](int kt) {
        #pragma unroll
        for (int i = 0; i < 4; ++i) {
            int c    = i * 256 + tid;
            int row  = c >> 3;
            int slot = (c & 7) ^ (row & 7);
            const u16* ga = A  + (size_t)(rowA0 + row) * K + kt * 64 + slot * 8;
            const u16* gb = Bt + (size_t)(colB0 + row) * K + kt * 64 + slot * 8;
            int ldsOff = i * 4096 + wid * 1024;
            __builtin_amdgcn_global_load_lds((gu32*)ga, (su32*)(smem + ldsOff),         16, 0, 0);
            __builtin_amdgcn_global_load_lds((gu32*)gb, (su32*)(smem + 16384 + ldsOff), 16, 0, 0);
        }
    };

    f32x4 acc[4][4];
    #pragma unroll
    for (int m = 0; m < 4; ++m)
        #pragma unroll
        for (int n = 0; n < 4; ++n) acc[m][n] = f32x4{0.f, 0.f, 0.f, 0.f};

    for (int kt = 0; kt < KT; ++kt) {
        stage(kt);
        __syncthreads();
        #pragma unroll
        for (int ks = 0; ks < 2; ++ks) {
            bf16x8 af[4], bfr[4];
            #pragma unroll
            for (int m = 0; m < 4; ++m) {
                int row = wm * 64 + m * 16 + lr;
                int kbyte = (ks * 64 + hi * 16) ^ ((row & 7) << 4);
                af[m] = *(const bf16x8*)(smem + row * 128 + kbyte);
            }
            #pragma unroll
            for (int n = 0; n < 4; ++n) {
                int row = wn * 64 + n * 16 + lr;
                int kbyte = (ks * 64 + hi * 16) ^ ((row & 7) << 4);
                bfr[n] = *(const bf16x8*)(smem + 16384 + row * 128 + kbyte);
            }
            #pragma unroll
            for (int m = 0; m < 4; ++m)
                #pragma unroll
                for (int n = 0; n < 4; ++n)
                    acc[m][n] = __builtin_amdgcn_mfma_f32_16x16x32_bf16(af[m], bfr[n], acc[m][n], 0, 0, 0);
        }
        __syncthreads();
    }

    #pragma unroll
    for (int m = 0; m < 4; ++m) {
        #pragma unroll
        for (int n = 0; n < 4; ++n) {
            int gcol = colB0 + wn * 64 + n * 16 + lr;
            #pragma unroll
            for (int r = 0; r < 4; ++r) {
                int grow = rowA0 + wm * 64 + m * 16 + hi * 4 + r;
                float v = acc[m][n][r];
                if constexpr (EPI == 0) {
                    v = tanhf(v + bias[gcol]);
                } else {
                    v = v + bias[gcol] + resid[(size_t)grow * ldOut + gcol];
                }
                outB[(size_t)grow * ldOut + gcol] = f2bf(v);
            }
        }
    }
}

// ---------------- head GEMM: 128x256xK512, BK=32, ONE barrier per K-tile ------------
// 8 waves (2Mx4N), 72KB LDS (3 bufs x 24KB) -> 2 blocks/CU. Loop iter:
//   WAITB(3) [vmcnt(3)+lgkmcnt(0)+s_barrier] -> compute(kt) -> stage(kt+2).
// stage(kt+2) overwrites buf((kt-1)%3) whose reads completed before this barrier's
// lgkmcnt(0); vmcnt(3) leaves exactly stage(kt+1) (3 loads) in flight. Never vmcnt(0)
// in steady state; barrier count halved vs r7. Epilogue stride 260 (hi-groups on
// distinct banks), lgkm-qualified pass barriers.

#define ENDP { asm volatile("s_waitcnt lgkmcnt(0)" ::: "memory");                     \
               __builtin_amdgcn_sched_barrier(0);                                     \
               __builtin_amdgcn_s_barrier();                                          \
               __builtin_amdgcn_sched_barrier(0); }

#define WAITB(N) { asm volatile("s_waitcnt vmcnt(" #N ") lgkmcnt(0)" ::: "memory");   \
                   __builtin_amdgcn_sched_barrier(0);                                 \
                   __builtin_amdgcn_s_barrier();                                      \
                   __builtin_amdgcn_sched_barrier(0); }

__global__ __launch_bounds__(512, 2)
void head_kernel(const u16* __restrict__ A, const u16* __restrict__ Bt,
                 const float* __restrict__ bias, float* __restrict__ outF,
                 int colStart, int nbx)
{
    __shared__ char smem[73728];            // 3 x (A 8KB + B 16KB); epilogue reuses
    const int tid  = threadIdx.x;
    const int wid  = tid >> 6;
    const int lane = tid & 63;
    const int wm   = wid >> 2, wn = wid & 3;
    const int lr   = lane & 15;
    const int hi   = lane >> 4;

    // block mapping: bijective XCD chunks, by-fastest (B-panel L2-resident)
    const int nwg = nbx * 64;
    const int per = nwg >> 3;               // nwg % 8 == 0
    const int wg  = (blockIdx.x & 7) * per + (blockIdx.x >> 3);
    const int bx  = wg >> 6;
    const int by  = wg & 63;
    const int rowA0 = by * 128;
    const int colB0 = bx * 256;

    auto stageT = [&](int kt, int buf) {
        char* Ab = smem + buf * 24576;
        char* Bb = Ab + 8192;
        {   // A half: 128 rows x 32 k -> 512 cells, 1 load/thread
            int row = tid >> 2, sc = tid & 3, gs = sc ^ ((row >> 1) & 3);
            const u16* ga = A + (size_t)(rowA0 + row) * C_ + kt * 32 + gs * 8;
            __builtin_amdgcn_global_load_lds((gu32*)ga, (su32*)(Ab + wid * 1024), 16, 0, 0);
        }
        #pragma unroll
        for (int i = 0; i < 2; ++i) {       // B half: 256 rows -> 1024 cells, 2/thread
            int u = i * 512 + tid;
            int row = u >> 2, sc = u & 3, gs = sc ^ ((row >> 1) & 3);
            const u16* gb = Bt + (size_t)(colB0 + row) * C_ + kt * 32 + gs * 8;
            __builtin_amdgcn_global_load_lds((gu32*)gb, (su32*)(Bb + i * 8192 + wid * 1024), 16, 0, 0);
        }
    };

    f32x4 acc[4][4];
    #pragma unroll
    for (int m = 0; m < 4; ++m)
        #pragma unroll
        for (int n = 0; n < 4; ++n) acc[m][n] = f32x4{0.f, 0.f, 0.f, 0.f};

    auto computeT = [&](int buf) {
        const char* Ab = smem + buf * 24576;
        const char* Bb = Ab + 8192;
        bf16x8 af[4], bfr[4];
        #pragma unroll
        for (int m = 0; m < 4; ++m) {
            int r = wm * 64 + m * 16 + lr;
            af[m] = *(const bf16x8*)(Ab + (r * 4 + (hi ^ ((r >> 1) & 3))) * 16);
        }
        #pragma unroll
        for (int n = 0; n < 4; ++n) {
            int r = wn * 64 + n * 16 + lr;
            bfr[n] = *(const bf16x8*)(Bb + (r * 4 + (hi ^ ((r >> 1) & 3))) * 16);
        }
        __builtin_amdgcn_s_setprio(1);
        #pragma unroll
        for (int m = 0; m < 4; ++m)
            #pragma unroll
            for (int n = 0; n < 4; ++n)
                acc[m][n] = __builtin_amdgcn_mfma_f32_16x16x32_bf16(af[m], bfr[n], acc[m][n], 0, 0, 0);
        __builtin_amdgcn_s_setprio(0);
    };

    // prologue: tiles 0,1 in flight (3 loads/thread each)
    stageT(0, 0);
    stageT(1, 1);
    // main: ONE barrier per tile, 16 K-tiles of 32
    for (int kt = 0; kt < 14; ++kt) {
        WAITB(3)                            // buf kt resident; stage(kt+1) in flight
        computeT(kt % 3);
        stageT(kt + 2, (kt + 2) % 3);       // overwrites buf((kt-1)%3), reads done
    }
    WAITB(3)
    computeT(14 % 3);
    WAITB(0)
    computeT(15 % 3);

    // ---- epilogue: 4 passes of 32 rows x 256 cols, LDS-staged, 16B-aligned stores --
    float* ebuf = (float*)smem;             // 32 x 260 floats = 33.3KB
    float biasr[4];
    #pragma unroll
    for (int nf = 0; nf < 4; ++nf) {
        int vc = colStart + colB0 + wn * 64 + nf * 16 + lr;
        biasr[nf] = (vc < V_) ? bias[vc] : 0.f;
    }
    const int er2 = tid >> 4;               // 0..31: output row owner
    const int kk  = tid & 15;
    #pragma unroll
    for (int mf = 0; mf < 4; ++mf) {
        ENDP                                // prior pass reads (and K-loop tail) done
        #pragma unroll
        for (int nf = 0; nf < 4; ++nf) {
            int ec = wn * 64 + nf * 16 + lr;
            int er = wm * 16 + hi * 4;
            #pragma unroll
            for (int r = 0; r < 4; ++r)
                ebuf[(er + r) * 260 + ec] = acc[mf][nf][r] + biasr[nf];
        }
        ENDP                                // writes visible to all waves
        long grow = rowA0 + (er2 >> 4) * 64 + mf * 16 + (er2 & 15);
        long S    = grow * V_ + colStart + colB0;   // f32 flat index of col 0
        long a0   = (S + 3) & ~3L;                  // 16B-aligned start
        int  sh   = (int)(a0 - S);                  // 0..3
        const float* rowp = ebuf + er2 * 260;
        if (kk == 0) {
            for (int e = 0; e < sh; ++e) {          // head elems (cached: L2 merge)
                int vc = colStart + colB0 + e;
                if (vc < V_) outF[S + e] = rowp[e];
            }
        }
        #pragma unroll
        for (int j = 0; j < 4; ++j) {
            int  cb = sh + (kk + j * 16) * 4;       // block-local col of chunk
            long g  = a0 + (long)(kk + j * 16) * 4;
            int  vc = colStart + colB0 + cb;        // vocab col of first elem
            if (cb + 3 <= 255 && vc + 3 < V_) {
                f32x4a t = { rowp[cb], rowp[cb + 1], rowp[cb + 2], rowp[cb + 3] };
                __builtin_nontemporal_store(t, (f32x4a*)(outF + g));
            } else {
                #pragma unroll
                for (int e = 0; e < 4; ++e)
                    if (cb + e <= 255 && vc + e < V_)
                        outF[g + e] = rowp[cb + e];  // cached boundary stores
            }
        }
    }
}

// ------------------------------------------------------------------------------------
extern "C" void kernel_launch(void* const* d_in, const int* in_sizes, int n_in,
                              void* d_out, int out_size, void* d_ws, size_t ws_size,
                              hipStream_t stream)
{
    const int*   x      = (const int*)  d_in[0];
    const float* wte    = (const float*)d_in[1];
    const float* wpe    = (const float*)d_in[2];
    const float* w_fc   = (const float*)d_in[3];
    const float* b_fc   = (const float*)d_in[4];
    const float* w_proj = (const float*)d_in[5];
    const float* b_proj = (const float*)d_in[6];
    const float* w_head = (const float*)d_in[7];
    const float* b_head = (const float*)d_in[8];
    float* out = (float*)d_out;

    // Scratch inside d_out (dead before the head GEMM overwrites d_out)
    char*  ob   = (char*)d_out;
    float* emb  = (float*)(ob);                    // 16 MB
    float* h1f  = (float*)(ob + 16 * MB_);         // 16 MB
    u16*   h1b  = (u16*)  (ob + 32 * MB_);         //  8 MB
    u16*   actb = (u16*)  (ob + 40 * MB_);         // 32 MB
    u16*   wfct = (u16*)  (ob + 72 * MB_);         //  2 MB
    u16*   wprt = (u16*)  (ob + 74 * MB_);         //  2 MB
    float* S    = (float*)(ob + 76 * MB_);         // 128 KB
    float* P    = (float*)(ob + 76 * MB_ + 128 * 1024);

    // ws: only what must survive while the head GEMM writes d_out
    u16* h2b = (u16*)d_ws;                         // 8 MB
    u16* wht = (u16*)((char*)d_ws + 8 * MB_);      // head weight chunk (bf16, transposed)

    long availCols = 0;
    if (ws_size > 8 * MB_ + 512 * 1024)
        availCols = (long)((ws_size - 8 * MB_) / (C_ * 2));
    int chunk = (int)(availCols & ~255L);
    if (chunk < 256)   chunk = 256;
    if (chunk > VPAD_) chunk = VPAD_;

    // weights -> bf16 transposed (N-major, K-contiguous)
    tconv_kernel<<<dim3(H_ / 32, C_ / 32), dim3(32, 8), 0, stream>>>(w_fc,   wfct, C_, H_, 0, H_);
    tconv_kernel<<<dim3(C_ / 32, H_ / 32), dim3(32, 8), 0, stream>>>(w_proj, wprt, H_, C_, 0, C_);

    // embedding + causal BoW
    emb_kernel <<<128, 256, 0, stream>>>(x, wte, wpe, emb, S);
    scan_kernel<<<8,   256, 0, stream>>>(S, P);
    bow_kernel <<<128, 256, 0, stream>>>(emb, P, h1f, h1b);

    // MLP
    gemm_kernel<0><<<(H_ / 128) * (BT_ / 128), 256, 0, stream>>>(
        h1b, wfct, BT_, H_, C_, b_fc, nullptr, actb, H_);
    gemm_kernel<1><<<(C_ / 128) * (BT_ / 128), 256, 0, stream>>>(
        actb, wprt, BT_, C_, H_, b_proj, h1f, h2b, C_);

    // head: V processed in ws-sized column chunks
    for (int cs = 0; cs < VPAD_; cs += chunk) {
        int nc = VPAD_ - cs < chunk ? VPAD_ - cs : chunk;
        tconv_kernel<<<dim3(nc / 32, C_ / 32), dim3(32, 8), 0, stream>>>(
            w_head, wht, C_, V_, cs, nc);
        head_kernel<<<(nc / 256) * 64, 512, 0, stream>>>(
            h2b, wht, b_head, out, cs, nc / 256);
    }
}